// Round 1
// baseline (254.255 us; speedup 1.0000x reference)
//
#include <hip/hip_runtime.h>
#include <stdint.h>
#include <stddef.h>

// Problem constants (B=2, S=2048, D=2048, H=16, KVH=4, HD=128)
#define S_LEN  2048
#define NH     16
#define NKVH   4
#define HD_    128
#define DMODEL 2048
#define NQKV   3072      // H*HD + 2*KVH*HD
#define MROWS  4096      // B*S

typedef __attribute__((ext_vector_type(8))) __bf16 bf16x8;
typedef __attribute__((ext_vector_type(4))) __bf16 bf16x4;
typedef __attribute__((ext_vector_type(4))) float  f32x4;

#define MFMA16(a, b, c) __builtin_amdgcn_mfma_f32_16x16x32_bf16((a), (b), (c), 0, 0, 0)

__device__ __forceinline__ void gload16(const void* g, void* l) {
  __builtin_amdgcn_global_load_lds((const __attribute__((address_space(1))) void*)g,
                                   (__attribute__((address_space(3))) void*)l,
                                   16, 0, 0);
}

__device__ __forceinline__ float bf2f(uint16_t u) {
  uint32_t x = ((uint32_t)u) << 16;
  return __builtin_bit_cast(float, x);
}
__device__ __forceinline__ uint16_t f2bf(float f) {
  uint32_t u = __builtin_bit_cast(uint32_t, f);
  uint32_t r = (u + 0x7FFFu + ((u >> 16) & 1u)) >> 16;
  return (uint16_t)r;
}

// ---------------------------------------------------------------------------
// 1) x (f32) -> xb (bf16), exact-size grid: 8192 blocks * 256 thr * 4 elems
// ---------------------------------------------------------------------------
__global__ void cvt_x_kernel(const float* __restrict__ x, __bf16* __restrict__ xb) {
  size_t i = (size_t)blockIdx.x * 256 + threadIdx.x;       // float4 index
  const float4* xv = (const float4*)x;
  float4 v = xv[i];
  bf16x4 o;
  o[0] = (__bf16)v.x; o[1] = (__bf16)v.y; o[2] = (__bf16)v.z; o[3] = (__bf16)v.w;
  *(bf16x4*)(xb + i * 4) = o;
}

// ---------------------------------------------------------------------------
// 2) W [K][N] f32  ->  WT [N][K] bf16  (LDS-tiled 64x64 transpose)
// ---------------------------------------------------------------------------
__global__ void tw_kernel(const float* __restrict__ W, int ldw,
                          __bf16* __restrict__ WT, int ldt) {
  __shared__ float tile[64][65];
  const int k0 = blockIdx.x * 64, n0 = blockIdx.y * 64;
  const int tid = threadIdx.x;
#pragma unroll
  for (int r = 0; r < 16; ++r) {
    int idx = r * 256 + tid;
    int kr = idx >> 6, nc = idx & 63;
    tile[kr][nc] = W[(size_t)(k0 + kr) * ldw + n0 + nc];
  }
  __syncthreads();
#pragma unroll
  for (int r = 0; r < 16; ++r) {
    int idx = r * 256 + tid;
    int nr = idx >> 6, kc = idx & 63;
    WT[(size_t)(n0 + nr) * ldt + k0 + kc] = (__bf16)tile[kc][nr];
  }
}

// ---------------------------------------------------------------------------
// 3/7) bf16 GEMM: C[M][N] = A[M][K] * Bt[N][K]^T.  128x128 tile, BK=64,
// 4 waves (2x2), 4x4 16x16x32 frags/wave.  global_load_lds(16B) staging with
// XOR swizzle applied on the *source* address (LDS dest linear) and on reads.
// ---------------------------------------------------------------------------
template <int OUT_F32>
__global__ __launch_bounds__(256, 2) void gemm_kernel(
    const __bf16* __restrict__ A, int lda,
    const __bf16* __restrict__ Bt, int ldb,
    void* __restrict__ Cout, int ldc, int Kdim) {
  __shared__ __attribute__((aligned(16))) __bf16 As[128 * 64];
  __shared__ __attribute__((aligned(16))) __bf16 Bs[128 * 64];
  const int tid = threadIdx.x;
  const int w = tid >> 6, l = tid & 63, lg = l >> 4, lr = l & 15;
  const int wm = w >> 1, wn = w & 1;
  const int m0 = blockIdx.y * 128, n0 = blockIdx.x * 128;

  f32x4 acc[4][4] = {};

  for (int k0 = 0; k0 < Kdim; k0 += 64) {
#pragma unroll
    for (int t = 0; t < 4; ++t) {
      int o = (t * 256 + tid) * 16;       // linear byte offset in 16KB tile
      int row = o >> 7;                   // 128B rows (64 bf16)
      int slot = (o >> 4) & 7;
      int sw = slot ^ (row & 7);          // involution: pre-swizzled source
      char* lbase = (char*)nullptr;
      lbase = (char*)As + t * 4096 + (w << 10);
      gload16(A + (size_t)(m0 + row) * lda + k0 + sw * 8, lbase);
      lbase = (char*)Bs + t * 4096 + (w << 10);
      gload16(Bt + (size_t)(n0 + row) * ldb + k0 + sw * 8, lbase);
    }
    __syncthreads();
#pragma unroll
    for (int c = 0; c < 2; ++c) {
      bf16x8 af[4];
#pragma unroll
      for (int mi = 0; mi < 4; ++mi) {
        int row = wm * 64 + mi * 16 + lr;
        int slot = (c * 4 + lg) ^ (row & 7);
        af[mi] = *(const bf16x8*)((const char*)As + row * 128 + slot * 16);
      }
#pragma unroll
      for (int ni = 0; ni < 4; ++ni) {
        int rn = wn * 64 + ni * 16 + lr;
        int slot = (c * 4 + lg) ^ (rn & 7);
        bf16x8 bfr = *(const bf16x8*)((const char*)Bs + rn * 128 + slot * 16);
#pragma unroll
        for (int mi = 0; mi < 4; ++mi)
          acc[mi][ni] = MFMA16(af[mi], bfr, acc[mi][ni]);
      }
    }
    __syncthreads();
  }

#pragma unroll
  for (int mi = 0; mi < 4; ++mi)
#pragma unroll
    for (int ni = 0; ni < 4; ++ni)
#pragma unroll
      for (int i = 0; i < 4; ++i) {
        int r = m0 + wm * 64 + mi * 16 + lg * 4 + i;
        int cc = n0 + wn * 64 + ni * 16 + lr;
        if (OUT_F32)
          ((float*)Cout)[(size_t)r * ldc + cc] = acc[mi][ni][i];
        else
          ((__bf16*)Cout)[(size_t)r * ldc + cc] = (__bf16)acc[mi][ni][i];
      }
}

// ---------------------------------------------------------------------------
// 4) RoPE in place on Q cols [0,2048) and K cols [2048,2560) of qkv (bf16).
// Q additionally scaled by 1/sqrt(HD).  1280 pairs per row, 256 threads.
// ---------------------------------------------------------------------------
__global__ void rope_kernel(__bf16* __restrict__ qkv,
                            const float* __restrict__ fc,
                            const float* __restrict__ fs) {
  const int row = blockIdx.x;            // b*S + s
  const int s = row & (S_LEN - 1);
  const int tid = threadIdx.x;
  const float qscale = 0.08838834764831845f;  // 1/sqrt(128)
#pragma unroll
  for (int rep = 0; rep < 5; ++rep) {
    int pid = rep * 256 + tid;           // 0..1279
    int col, j;
    float scale;
    if (pid < 1024) { int hh = pid >> 6; j = pid & 63; col = hh * HD_ + 2 * j; scale = qscale; }
    else { int p2 = pid - 1024; int kv = p2 >> 6; j = p2 & 63; col = DMODEL + kv * HD_ + 2 * j; scale = 1.0f; }
    uint32_t u = *(const uint32_t*)(qkv + (size_t)row * NQKV + col);
    float xr = bf2f((uint16_t)(u & 0xFFFFu));
    float xi = bf2f((uint16_t)(u >> 16));
    float c = fc[s * 64 + j], sn = fs[s * 64 + j];
    float orr = (xr * c - xi * sn) * scale;
    float oi  = (xr * sn + xi * c) * scale;
    uint32_t res = (uint32_t)f2bf(orr) | ((uint32_t)f2bf(oi) << 16);
    *(uint32_t*)(qkv + (size_t)row * NQKV + col) = res;
  }
}

// ---------------------------------------------------------------------------
// 5) V part of qkv (cols [2560,3072)) -> VT [b][kvh][d][s] bf16 (64x64 tiles)
// ---------------------------------------------------------------------------
__global__ void vt_kernel(const __bf16* __restrict__ qkv, __bf16* __restrict__ VT) {
  __shared__ uint16_t tile[64][66];
  const int bkv = blockIdx.z;            // b*4 + kvh
  const int b = bkv >> 2, kv = bkv & 3;
  const int s0 = blockIdx.x * 64, d0 = blockIdx.y * 64;
  const int tid = threadIdx.x;
#pragma unroll
  for (int r = 0; r < 16; ++r) {
    int idx = r * 256 + tid;
    int sr = idx >> 6, dc = idx & 63;
    tile[sr][dc] = *(const uint16_t*)(qkv + (size_t)(b * S_LEN + s0 + sr) * NQKV +
                                      (DMODEL + NKVH * HD_) + kv * HD_ + d0 + dc);
  }
  __syncthreads();
#pragma unroll
  for (int r = 0; r < 16; ++r) {
    int idx = r * 256 + tid;
    int dr = idx >> 6, sc = idx & 63;
    *(uint16_t*)(VT + (size_t)(bkv * HD_ + d0 + dr) * S_LEN + s0 + sc) = tile[sc][dr];
  }
}

// ---------------------------------------------------------------------------
// 6) Flash attention (non-causal, full S).  Block = 4 waves * 32 q-rows.
// Q frags in regs; K tile [64][128] and VT tile [128][64] staged via swizzled
// global_load_lds; online softmax with shfl_xor row-reduce; P via padded LDS.
// Writes attn-out bf16 [b*S][H*HD].
// ---------------------------------------------------------------------------
__global__ __launch_bounds__(256, 2) void attn_kernel(
    const __bf16* __restrict__ qkv, const __bf16* __restrict__ VT,
    __bf16* __restrict__ out) {
  __shared__ __attribute__((aligned(16))) __bf16 Ks[64 * 128];
  __shared__ __attribute__((aligned(16))) __bf16 Vs[128 * 64];
  __shared__ __attribute__((aligned(16))) __bf16 Ps[4][32][72];
  const int tid = threadIdx.x;
  const int w = tid >> 6, l = tid & 63, lg = l >> 4, lr = l & 15;
  const int bh = blockIdx.y;             // 0..31
  const int b = bh >> 4, h = bh & 15, kvh = h >> 2;
  const int q0 = blockIdx.x * 128 + w * 32;   // wave's first q row within S

  // Q fragments: rows mt*16+lr, k-chunk c (d = c*32 + lg*8)
  bf16x8 aq[2][4];
#pragma unroll
  for (int mt = 0; mt < 2; ++mt)
#pragma unroll
    for (int c = 0; c < 4; ++c)
      aq[mt][c] = *(const bf16x8*)(qkv + (size_t)(b * S_LEN + q0 + mt * 16 + lr) * NQKV +
                                   h * HD_ + c * 32 + lg * 8);

  f32x4 o_acc[2][8] = {};
  float mrow[2][4], lrow[2][4];
#pragma unroll
  for (int mt = 0; mt < 2; ++mt)
#pragma unroll
    for (int i = 0; i < 4; ++i) { mrow[mt][i] = -1e30f; lrow[mt][i] = 0.0f; }

  const __bf16* Kbase = qkv + (size_t)b * S_LEN * NQKV + DMODEL + kvh * HD_;
  const __bf16* Vbase = VT + (size_t)(b * NKVH + kvh) * (HD_ * S_LEN);

  for (int kt = 0; kt < S_LEN / 64; ++kt) {
    // ---- stage K (64 rows x 256B) and V^T (128 rows x 128B), swizzled src
#pragma unroll
    for (int t = 0; t < 4; ++t) {
      int o = (t * 256 + tid) * 16;
      {
        int row = o >> 8; int slot = (o >> 4) & 15; int sw = slot ^ (row & 7);
        gload16(Kbase + (size_t)(kt * 64 + row) * NQKV + sw * 8,
                (char*)Ks + t * 4096 + (w << 10));
      }
      {
        int row = o >> 7; int slot = (o >> 4) & 7; int sw = slot ^ (row & 7);
        gload16(Vbase + (size_t)row * S_LEN + kt * 64 + sw * 8,
                (char*)Vs + t * 4096 + (w << 10));
      }
    }
    __syncthreads();

    // ---- QK^T: sc[mt][tt], col t = tt*16+lr, row q = mt*16 + lg*4+i
    f32x4 sc[2][4] = {};
#pragma unroll
    for (int tt = 0; tt < 4; ++tt) {
#pragma unroll
      for (int c = 0; c < 4; ++c) {
        int trow = tt * 16 + lr;
        int slot = (c * 4 + lg) ^ (trow & 7);
        bf16x8 kf = *(const bf16x8*)((const char*)Ks + trow * 256 + slot * 16);
        sc[0][tt] = MFMA16(aq[0][c], kf, sc[0][tt]);
        sc[1][tt] = MFMA16(aq[1][c], kf, sc[1][tt]);
      }
    }

    // ---- online softmax
    float pmax[2][4];
#pragma unroll
    for (int mt = 0; mt < 2; ++mt)
#pragma unroll
      for (int i = 0; i < 4; ++i) {
        float m0v = fmaxf(fmaxf(sc[mt][0][i], sc[mt][1][i]),
                          fmaxf(sc[mt][2][i], sc[mt][3][i]));
        pmax[mt][i] = m0v;
      }
#pragma unroll
    for (int mask = 1; mask < 16; mask <<= 1)
#pragma unroll
      for (int mt = 0; mt < 2; ++mt)
#pragma unroll
        for (int i = 0; i < 4; ++i)
          pmax[mt][i] = fmaxf(pmax[mt][i], __shfl_xor(pmax[mt][i], mask));

    float sf[2][4];
#pragma unroll
    for (int mt = 0; mt < 2; ++mt)
#pragma unroll
      for (int i = 0; i < 4; ++i) {
        float mn = fmaxf(mrow[mt][i], pmax[mt][i]);
        sf[mt][i] = __expf(mrow[mt][i] - mn);
        mrow[mt][i] = mn;
      }

    float pv_[2][4][4];
    float rs[2][4] = {};
#pragma unroll
    for (int mt = 0; mt < 2; ++mt)
#pragma unroll
      for (int tt = 0; tt < 4; ++tt)
#pragma unroll
        for (int i = 0; i < 4; ++i) {
          float p = __expf(sc[mt][tt][i] - mrow[mt][i]);
          pv_[mt][tt][i] = p;
          rs[mt][i] += p;
        }
#pragma unroll
    for (int mask = 1; mask < 16; mask <<= 1)
#pragma unroll
      for (int mt = 0; mt < 2; ++mt)
#pragma unroll
        for (int i = 0; i < 4; ++i)
          rs[mt][i] += __shfl_xor(rs[mt][i], mask);

#pragma unroll
    for (int mt = 0; mt < 2; ++mt)
#pragma unroll
      for (int i = 0; i < 4; ++i)
        lrow[mt][i] = lrow[mt][i] * sf[mt][i] + rs[mt][i];

    // rescale O
#pragma unroll
    for (int mt = 0; mt < 2; ++mt)
#pragma unroll
      for (int nt = 0; nt < 8; ++nt)
#pragma unroll
        for (int i = 0; i < 4; ++i)
          o_acc[mt][nt][i] *= sf[mt][i];

    // ---- P -> LDS (bf16), per-wave region, padded stride 72
#pragma unroll
    for (int mt = 0; mt < 2; ++mt)
#pragma unroll
      for (int tt = 0; tt < 4; ++tt)
#pragma unroll
        for (int i = 0; i < 4; ++i)
          Ps[w][mt * 16 + lg * 4 + i][tt * 16 + lr] = (__bf16)pv_[mt][tt][i];

    // ---- PV: O[q][d] += P[q][t] * V[t][d]
#pragma unroll
    for (int c2 = 0; c2 < 2; ++c2) {
      bf16x8 pa0 = *(const bf16x8*)&Ps[w][lr][c2 * 32 + lg * 8];
      bf16x8 pa1 = *(const bf16x8*)&Ps[w][16 + lr][c2 * 32 + lg * 8];
#pragma unroll
      for (int nt = 0; nt < 8; ++nt) {
        int drow = nt * 16 + lr;
        int slot = (c2 * 4 + lg) ^ (drow & 7);
        bf16x8 vf = *(const bf16x8*)((const char*)Vs + drow * 128 + slot * 16);
        o_acc[0][nt] = MFMA16(pa0, vf, o_acc[0][nt]);
        o_acc[1][nt] = MFMA16(pa1, vf, o_acc[1][nt]);
      }
    }
    __syncthreads();
  }

  // ---- epilogue: divide by row sums, write bf16 attn-out [b*S][H*HD]
  float rinv[2][4];
#pragma unroll
  for (int mt = 0; mt < 2; ++mt)
#pragma unroll
    for (int i = 0; i < 4; ++i) rinv[mt][i] = 1.0f / lrow[mt][i];
#pragma unroll
  for (int mt = 0; mt < 2; ++mt)
#pragma unroll
    for (int nt = 0; nt < 8; ++nt)
#pragma unroll
      for (int i = 0; i < 4; ++i)
        out[(size_t)(b * S_LEN + q0 + mt * 16 + lg * 4 + i) * DMODEL +
            h * HD_ + nt * 16 + lr] = (__bf16)(o_acc[mt][nt][i] * rinv[mt][i]);
}

// ---------------------------------------------------------------------------
extern "C" void kernel_launch(void* const* d_in, const int* in_sizes, int n_in,
                              void* d_out, int out_size, void* d_ws, size_t ws_size,
                              hipStream_t stream) {
  const float* x  = (const float*)d_in[0];
  const float* fc = (const float*)d_in[1];
  const float* fs = (const float*)d_in[2];
  const float* wq = (const float*)d_in[3];
  const float* wk = (const float*)d_in[4];
  const float* wv = (const float*)d_in[5];
  const float* wo = (const float*)d_in[6];
  // d_in[7]/d_in[8] caches unused (start_pos==0, s==S), d_in[9] start_pos==0.

  char* ws = (char*)d_ws;
  __bf16* xb    = (__bf16*)(ws);                         // 16 MiB (reused as attn-out)
  __bf16* wqkvT = (__bf16*)(ws + (16u << 20));           // 12 MiB: [3072][2048]
  __bf16* woT   = (__bf16*)(ws + (28u << 20));           //  8 MiB: [2048][2048]
  __bf16* qkv   = (__bf16*)(ws + (36u << 20));           // 24 MiB: [4096][3072]
  __bf16* VT    = (__bf16*)(ws + (60u << 20));           //  4 MiB: [2][4][128][2048]

  // 1) casts + weight transposes
  cvt_x_kernel<<<8192, 256, 0, stream>>>(x, xb);
  {
    dim3 g(32, 32); tw_kernel<<<g, 256, 0, stream>>>(wq, 2048, wqkvT, 2048);
  }
  {
    dim3 g(32, 8);
    tw_kernel<<<g, 256, 0, stream>>>(wk, 512, wqkvT + (size_t)2048 * 2048, 2048);
    tw_kernel<<<g, 256, 0, stream>>>(wv, 512, wqkvT + (size_t)2560 * 2048, 2048);
  }
  {
    dim3 g(32, 32); tw_kernel<<<g, 256, 0, stream>>>(wo, 2048, woT, 2048);
  }
  // 2) fused QKV projection -> qkv bf16 [4096][3072]
  {
    dim3 g(NQKV / 128, MROWS / 128);
    gemm_kernel<0><<<g, 256, 0, stream>>>(xb, 2048, wqkvT, 2048, qkv, NQKV, 2048);
  }
  // 3) RoPE on Q,K (Q scaled by 1/sqrt(HD))
  rope_kernel<<<MROWS, 256, 0, stream>>>(qkv, fc, fs);
  // 4) V -> V^T
  {
    dim3 g(32, 2, 8); vt_kernel<<<g, 256, 0, stream>>>(qkv, VT);
  }
  // 5) flash attention -> xb (attn-out bf16 [4096][2048])
  {
    dim3 g(S_LEN / 128, 32); attn_kernel<<<g, 256, 0, stream>>>(qkv, VT, xb);
  }
  // 6) output projection -> d_out f32
  {
    dim3 g(DMODEL / 128, MROWS / 128);
    gemm_kernel<1><<<g, 256, 0, stream>>>(xb, 2048, woT, 2048, d_out, 2048, 2048);
  }
}

// Round 3
// 204.865 us; speedup vs baseline: 1.2411x; 1.2411x over previous
//
#include <hip/hip_runtime.h>
#include <stdint.h>
#include <stddef.h>

// Problem constants (B=2, S=2048, D=2048, H=16, KVH=4, HD=128)
#define S_LEN  2048
#define NH     16
#define NKVH   4
#define HD_    128
#define DMODEL 2048
#define NQKV   3072      // H*HD + 2*KVH*HD
#define MROWS  4096      // B*S

typedef __attribute__((ext_vector_type(8)))  __bf16 bf16x8;
typedef __attribute__((ext_vector_type(4)))  __bf16 bf16x4;
typedef __attribute__((ext_vector_type(4)))  float  f32x4;
typedef __attribute__((ext_vector_type(16))) float  f32x16;

#define MFMA16(a, b, c) __builtin_amdgcn_mfma_f32_16x16x32_bf16((a), (b), (c), 0, 0, 0)
#define MFMA32(a, b, c) __builtin_amdgcn_mfma_f32_32x32x16_bf16((a), (b), (c), 0, 0, 0)

__device__ __forceinline__ void gload16(const void* g, void* l) {
  __builtin_amdgcn_global_load_lds((const __attribute__((address_space(1))) void*)g,
                                   (__attribute__((address_space(3))) void*)l,
                                   16, 0, 0);
}

__device__ __forceinline__ float bf2f(uint16_t u) {
  uint32_t x = ((uint32_t)u) << 16;
  return __builtin_bit_cast(float, x);
}
__device__ __forceinline__ uint16_t f2bf(float f) {
  uint32_t u = __builtin_bit_cast(uint32_t, f);
  uint32_t r = (u + 0x7FFFu + ((u >> 16) & 1u)) >> 16;
  return (uint16_t)r;
}

// packed f32x2 -> bf16x2 (no builtin on gfx950; guide T12)
__device__ __forceinline__ uint32_t cvtpk(float lo, float hi) {
  uint32_t d;
  asm("v_cvt_pk_bf16_f32 %0, %1, %2" : "=v"(d) : "v"(lo), "v"(hi));
  return d;
}
// v_permlane32_swap_b32: a[32:63] <-> b[0:31].  s_nop guards the
// VALU-write -> permlane cross-lane-read hazard (the hazard recognizer
// cannot see across separate asm blocks).  NOTE: a and b MUST be distinct
// SSA values — equal values coalesce to one VGPR and the swap self-cancels.
__device__ __forceinline__ void pswap(uint32_t& a, uint32_t& b) {
  asm("s_nop 1\n\tv_permlane32_swap_b32 %0, %1" : "+v"(a), "+v"(b));
}

// ---------------------------------------------------------------------------
// 1) x (f32) -> xb (bf16)
// ---------------------------------------------------------------------------
__global__ void cvt_x_kernel(const float* __restrict__ x, __bf16* __restrict__ xb) {
  size_t i = (size_t)blockIdx.x * 256 + threadIdx.x;       // float4 index
  const float4* xv = (const float4*)x;
  float4 v = xv[i];
  bf16x4 o;
  o[0] = (__bf16)v.x; o[1] = (__bf16)v.y; o[2] = (__bf16)v.z; o[3] = (__bf16)v.w;
  *(bf16x4*)(xb + i * 4) = o;
}

// ---------------------------------------------------------------------------
// 2) W [K][N] f32  ->  WT [N][K] bf16  (LDS-tiled 64x64 transpose)
// ---------------------------------------------------------------------------
__global__ void tw_kernel(const float* __restrict__ W, int ldw,
                          __bf16* __restrict__ WT, int ldt) {
  __shared__ float tile[64][65];
  const int k0 = blockIdx.x * 64, n0 = blockIdx.y * 64;
  const int tid = threadIdx.x;
#pragma unroll
  for (int r = 0; r < 16; ++r) {
    int idx = r * 256 + tid;
    int kr = idx >> 6, nc = idx & 63;
    tile[kr][nc] = W[(size_t)(k0 + kr) * ldw + n0 + nc];
  }
  __syncthreads();
#pragma unroll
  for (int r = 0; r < 16; ++r) {
    int idx = r * 256 + tid;
    int nr = idx >> 6, kc = idx & 63;
    WT[(size_t)(n0 + nr) * ldt + k0 + kc] = (__bf16)tile[kc][nr];
  }
}

// ---------------------------------------------------------------------------
// 3/7) bf16 GEMM: C[M][N] = A[M][K] * Bt[N][K]^T.  128x128 tile, BK=64,
// 4 waves (2x2), 4x4 16x16x32 frags/wave.  global_load_lds(16B) staging with
// XOR swizzle applied on the *source* address (LDS dest linear) and on reads.
// ---------------------------------------------------------------------------
template <int OUT_F32>
__global__ __launch_bounds__(256, 2) void gemm_kernel(
    const __bf16* __restrict__ A, int lda,
    const __bf16* __restrict__ Bt, int ldb,
    void* __restrict__ Cout, int ldc, int Kdim) {
  __shared__ __attribute__((aligned(16))) __bf16 As[128 * 64];
  __shared__ __attribute__((aligned(16))) __bf16 Bs[128 * 64];
  const int tid = threadIdx.x;
  const int w = tid >> 6, l = tid & 63, lg = l >> 4, lr = l & 15;
  const int wm = w >> 1, wn = w & 1;
  const int m0 = blockIdx.y * 128, n0 = blockIdx.x * 128;

  f32x4 acc[4][4] = {};

  for (int k0 = 0; k0 < Kdim; k0 += 64) {
#pragma unroll
    for (int t = 0; t < 4; ++t) {
      int o = (t * 256 + tid) * 16;       // linear byte offset in 16KB tile
      int row = o >> 7;                   // 128B rows (64 bf16)
      int slot = (o >> 4) & 7;
      int sw = slot ^ (row & 7);          // involution: pre-swizzled source
      char* lbase = (char*)nullptr;
      lbase = (char*)As + t * 4096 + (w << 10);
      gload16(A + (size_t)(m0 + row) * lda + k0 + sw * 8, lbase);
      lbase = (char*)Bs + t * 4096 + (w << 10);
      gload16(Bt + (size_t)(n0 + row) * ldb + k0 + sw * 8, lbase);
    }
    __syncthreads();
#pragma unroll
    for (int c = 0; c < 2; ++c) {
      bf16x8 af[4];
#pragma unroll
      for (int mi = 0; mi < 4; ++mi) {
        int row = wm * 64 + mi * 16 + lr;
        int slot = (c * 4 + lg) ^ (row & 7);
        af[mi] = *(const bf16x8*)((const char*)As + row * 128 + slot * 16);
      }
#pragma unroll
      for (int ni = 0; ni < 4; ++ni) {
        int rn = wn * 64 + ni * 16 + lr;
        int slot = (c * 4 + lg) ^ (rn & 7);
        bf16x8 bfr = *(const bf16x8*)((const char*)Bs + rn * 128 + slot * 16);
#pragma unroll
        for (int mi = 0; mi < 4; ++mi)
          acc[mi][ni] = MFMA16(af[mi], bfr, acc[mi][ni]);
      }
    }
    __syncthreads();
  }

#pragma unroll
  for (int mi = 0; mi < 4; ++mi)
#pragma unroll
    for (int ni = 0; ni < 4; ++ni)
#pragma unroll
      for (int i = 0; i < 4; ++i) {
        int r = m0 + wm * 64 + mi * 16 + lg * 4 + i;
        int cc = n0 + wn * 64 + ni * 16 + lr;
        if (OUT_F32)
          ((float*)Cout)[(size_t)r * ldc + cc] = acc[mi][ni][i];
        else
          ((__bf16*)Cout)[(size_t)r * ldc + cc] = (__bf16)acc[mi][ni][i];
      }
}

// ---------------------------------------------------------------------------
// 4) RoPE in place on Q cols [0,2048) and K cols [2048,2560) of qkv (bf16).
// Q additionally scaled by 1/sqrt(HD).
// ---------------------------------------------------------------------------
__global__ void rope_kernel(__bf16* __restrict__ qkv,
                            const float* __restrict__ fc,
                            const float* __restrict__ fs) {
  const int row = blockIdx.x;            // b*S + s
  const int s = row & (S_LEN - 1);
  const int tid = threadIdx.x;
  const float qscale = 0.08838834764831845f;  // 1/sqrt(128)
#pragma unroll
  for (int rep = 0; rep < 5; ++rep) {
    int pid = rep * 256 + tid;           // 0..1279
    int col, j;
    float scale;
    if (pid < 1024) { int hh = pid >> 6; j = pid & 63; col = hh * HD_ + 2 * j; scale = qscale; }
    else { int p2 = pid - 1024; int kv = p2 >> 6; j = p2 & 63; col = DMODEL + kv * HD_ + 2 * j; scale = 1.0f; }
    uint32_t u = *(const uint32_t*)(qkv + (size_t)row * NQKV + col);
    float xr = bf2f((uint16_t)(u & 0xFFFFu));
    float xi = bf2f((uint16_t)(u >> 16));
    float c = fc[s * 64 + j], sn = fs[s * 64 + j];
    float orr = (xr * c - xi * sn) * scale;
    float oi  = (xr * sn + xi * c) * scale;
    uint32_t res = (uint32_t)f2bf(orr) | ((uint32_t)f2bf(oi) << 16);
    *(uint32_t*)(qkv + (size_t)row * NQKV + col) = res;
  }
}

// ---------------------------------------------------------------------------
// 5) V part of qkv (cols [2560,3072)) -> VT [b][kvh][d][s] bf16 (64x64 tiles)
// ---------------------------------------------------------------------------
__global__ void vt_kernel(const __bf16* __restrict__ qkv, __bf16* __restrict__ VT) {
  __shared__ uint16_t tile[64][66];
  const int bkv = blockIdx.z;            // b*4 + kvh
  const int b = bkv >> 2, kv = bkv & 3;
  const int s0 = blockIdx.x * 64, d0 = blockIdx.y * 64;
  const int tid = threadIdx.x;
#pragma unroll
  for (int r = 0; r < 16; ++r) {
    int idx = r * 256 + tid;
    int sr = idx >> 6, dc = idx & 63;
    tile[sr][dc] = *(const uint16_t*)(qkv + (size_t)(b * S_LEN + s0 + sr) * NQKV +
                                      (DMODEL + NKVH * HD_) + kv * HD_ + d0 + dc);
  }
  __syncthreads();
#pragma unroll
  for (int r = 0; r < 16; ++r) {
    int idx = r * 256 + tid;
    int dr = idx >> 6, sc = idx & 63;
    *(uint16_t*)(VT + (size_t)(bkv * HD_ + d0 + dr) * S_LEN + s0 + sc) = tile[sc][dr];
  }
}

// ---------------------------------------------------------------------------
// 6) Flash attention — swapped-operand 32x32 MFMA structure (guide §B).
// 4 waves * 32 q-rows = 128 q/block.  Per wave:
//  - QK^T swapped: S^T = mfma32(K_frag, Q_frag)  -> lane owns q = lane&31,
//    holds 32 P values (kv = 32t + crow(r,hi), crow=(r&3)+8*(r>>2)+4*hi).
//  - softmax in-register: 31-op per-lane max tree + __shfl_xor(·,32) pair
//    combine (builtin — the round-2 asm-pswap-on-equal-values bug is gone);
//    defer-max (THR=8) skips O-rescale on most iters.
//  - P -> bf16 PV fragments via v_cvt_pk_bf16_f32 + permlane32_swap (no LDS).
//  - PV transposed: O^T = mfma32(V^T_frag, P^T_frag) so acc col = q = lane&31
//    and the softmax scalars apply uniformly per lane.
// ---------------------------------------------------------------------------
__global__ __launch_bounds__(256, 2) void attn_kernel(
    const __bf16* __restrict__ qkv, const __bf16* __restrict__ VT,
    __bf16* __restrict__ out) {
  __shared__ __attribute__((aligned(16))) __bf16 Ks[64 * 128];
  __shared__ __attribute__((aligned(16))) __bf16 Vs[128 * 64];
  const int tid = threadIdx.x;
  const int w = tid >> 6, l = tid & 63;
  const int qc = l & 31, hi = l >> 5;
  const int bh = blockIdx.y;             // 0..31
  const int b = bh >> 4, h = bh & 15, kvh = h >> 2;
  const int q0 = blockIdx.x * 128 + w * 32;   // wave's first q row within S

  // Q fragments (B-operand): lane holds Q[q0+qc][k = c*16 + hi*8 + j]
  bf16x8 aq[8];
#pragma unroll
  for (int c = 0; c < 8; ++c)
    aq[c] = *(const bf16x8*)(qkv + (size_t)(b * S_LEN + q0 + qc) * NQKV +
                             h * HD_ + c * 16 + hi * 8);

  f32x16 o_acc[4] = {};                  // O^T: rows d = 32dt + crow(r,hi), col q
  float m = -1e30f, lsum = 0.0f;

  const __bf16* Kbase = qkv + (size_t)b * S_LEN * NQKV + DMODEL + kvh * HD_;
  const __bf16* Vbase = VT + (size_t)(b * NKVH + kvh) * (HD_ * S_LEN);

  typedef union { uint32_t u[4]; bf16x8 v; } pfrag_t;

  for (int kt = 0; kt < S_LEN / 64; ++kt) {
    // ---- stage K (64 rows x 256B) and V^T (128 rows x 128B), swizzled src
#pragma unroll
    for (int t = 0; t < 4; ++t) {
      int o = (t * 256 + tid) * 16;
      {
        int row = o >> 8; int slot = (o >> 4) & 15; int sw = slot ^ (row & 7);
        gload16(Kbase + (size_t)(kt * 64 + row) * NQKV + sw * 8,
                (char*)Ks + t * 4096 + (w << 10));
      }
      {
        int row = o >> 7; int slot = (o >> 4) & 7; int sw = slot ^ (row & 7);
        gload16(Vbase + (size_t)row * S_LEN + kt * 64 + sw * 8,
                (char*)Vs + t * 4096 + (w << 10));
      }
    }
    __syncthreads();

    // ---- swapped QK^T: st[t] = S^T[kv = 32t + crow(r,hi)][q = qc]
    f32x16 st[2] = {};
    __builtin_amdgcn_s_setprio(1);
#pragma unroll
    for (int t = 0; t < 2; ++t) {
#pragma unroll
      for (int c = 0; c < 8; ++c) {
        int row = t * 32 + qc;
        int slot = (c * 2 + hi) ^ (row & 7);
        bf16x8 kf = *(const bf16x8*)((const char*)Ks + row * 256 + slot * 16);
        st[t] = MFMA32(kf, aq[c], st[t]);
      }
    }
    __builtin_amdgcn_s_setprio(0);

    // ---- in-register softmax (lane owns one q row; pair lane = other half)
    float pm = st[0][0];
#pragma unroll
    for (int t = 0; t < 2; ++t)
#pragma unroll
      for (int r = 0; r < 16; ++r) pm = fmaxf(pm, st[t][r]);
    pm = fmaxf(pm, __shfl_xor(pm, 32));

    if (__any(pm - m > 8.0f)) {          // defer-max (T13)
      float mn = fmaxf(m, pm);
      float sf = __expf(m - mn);
      lsum *= sf;
#pragma unroll
      for (int dt = 0; dt < 4; ++dt)
#pragma unroll
        for (int r = 0; r < 16; ++r) o_acc[dt][r] *= sf;
      m = mn;
    }

    float rsum = 0.0f;
#pragma unroll
    for (int t = 0; t < 2; ++t)
#pragma unroll
      for (int r = 0; r < 16; ++r) {
        st[t][r] = __expf(st[t][r] - m);
        rsum += st[t][r];
      }
    rsum += __shfl_xor(rsum, 32);
    lsum += rsum;

    // ---- pack P -> bf16 PV fragments (cvt_pk + permlane32_swap, T12)
    pfrag_t pf[4];
#pragma unroll
    for (int t = 0; t < 2; ++t)
#pragma unroll
      for (int half = 0; half < 2; ++half) {
        int bs = half * 8;
        uint32_t x0 = cvtpk(st[t][bs + 0], st[t][bs + 1]);
        uint32_t y0 = cvtpk(st[t][bs + 4], st[t][bs + 5]);
        uint32_t x1 = cvtpk(st[t][bs + 2], st[t][bs + 3]);
        uint32_t y1 = cvtpk(st[t][bs + 6], st[t][bs + 7]);
        pswap(x0, y0);
        pswap(x1, y1);
        pf[t * 2 + half].u[0] = x0;
        pf[t * 2 + half].u[1] = x1;
        pf[t * 2 + half].u[2] = y0;
        pf[t * 2 + half].u[3] = y1;
      }

    // ---- PV transposed: O^T += mfma32(V^T_frag, P^T_frag)
    __builtin_amdgcn_s_setprio(1);
#pragma unroll
    for (int dt = 0; dt < 4; ++dt) {
#pragma unroll
      for (int ks = 0; ks < 4; ++ks) {
        int row = dt * 32 + qc;
        int slot = (ks * 2 + hi) ^ (row & 7);
        bf16x8 vf = *(const bf16x8*)((const char*)Vs + row * 128 + slot * 16);
        o_acc[dt] = MFMA32(vf, pf[ks].v, o_acc[dt]);
      }
    }
    __builtin_amdgcn_s_setprio(0);
    __syncthreads();
  }

  // ---- epilogue: normalize, write bf16 attn-out [b*S][H*HD]
  float rinv = 1.0f / lsum;
  const size_t orow = (size_t)(b * S_LEN + q0 + qc) * DMODEL + h * HD_;
#pragma unroll
  for (int dt = 0; dt < 4; ++dt)
#pragma unroll
    for (int rg = 0; rg < 4; ++rg) {
      bf16x4 ov;
#pragma unroll
      for (int i = 0; i < 4; ++i)
        ov[i] = (__bf16)(o_acc[dt][rg * 4 + i] * rinv);
      int d = dt * 32 + rg * 8 + hi * 4;   // crow(rg*4+i,hi) = i + 8rg + 4hi
      *(bf16x4*)(out + orow + d) = ov;
    }
}

// ---------------------------------------------------------------------------
extern "C" void kernel_launch(void* const* d_in, const int* in_sizes, int n_in,
                              void* d_out, int out_size, void* d_ws, size_t ws_size,
                              hipStream_t stream) {
  const float* x  = (const float*)d_in[0];
  const float* fc = (const float*)d_in[1];
  const float* fs = (const float*)d_in[2];
  const float* wq = (const float*)d_in[3];
  const float* wk = (const float*)d_in[4];
  const float* wv = (const float*)d_in[5];
  const float* wo = (const float*)d_in[6];
  // d_in[7]/d_in[8] caches unused (start_pos==0, s==S), d_in[9] start_pos==0.

  char* ws = (char*)d_ws;
  __bf16* xb    = (__bf16*)(ws);                         // 16 MiB (reused as attn-out)
  __bf16* wqkvT = (__bf16*)(ws + (16u << 20));           // 12 MiB: [3072][2048]
  __bf16* woT   = (__bf16*)(ws + (28u << 20));           //  8 MiB: [2048][2048]
  __bf16* qkv   = (__bf16*)(ws + (36u << 20));           // 24 MiB: [4096][3072]
  __bf16* VT    = (__bf16*)(ws + (60u << 20));           //  4 MiB: [2][4][128][2048]

  // 1) casts + weight transposes
  cvt_x_kernel<<<8192, 256, 0, stream>>>(x, xb);
  {
    dim3 g(32, 32); tw_kernel<<<g, 256, 0, stream>>>(wq, 2048, wqkvT, 2048);
  }
  {
    dim3 g(32, 8);
    tw_kernel<<<g, 256, 0, stream>>>(wk, 512, wqkvT + (size_t)2048 * 2048, 2048);
    tw_kernel<<<g, 256, 0, stream>>>(wv, 512, wqkvT + (size_t)2560 * 2048, 2048);
  }
  {
    dim3 g(32, 32); tw_kernel<<<g, 256, 0, stream>>>(wo, 2048, woT, 2048);
  }
  // 2) fused QKV projection -> qkv bf16 [4096][3072]
  {
    dim3 g(NQKV / 128, MROWS / 128);
    gemm_kernel<0><<<g, 256, 0, stream>>>(xb, 2048, wqkvT, 2048, qkv, NQKV, 2048);
  }
  // 3) RoPE on Q,K (Q scaled by 1/sqrt(HD))
  rope_kernel<<<MROWS, 256, 0, stream>>>(qkv, fc, fs);
  // 4) V -> V^T
  {
    dim3 g(32, 2, 8); vt_kernel<<<g, 256, 0, stream>>>(qkv, VT);
  }
  // 5) flash attention -> xb (attn-out bf16 [4096][2048])
  {
    dim3 g(S_LEN / 128, 32); attn_kernel<<<g, 256, 0, stream>>>(qkv, VT, xb);
  }
  // 6) output projection -> d_out f32
  {
    dim3 g(DMODEL / 128, MROWS / 128);
    gemm_kernel<1><<<g, 256, 0, stream>>>(xb, 2048, woT, 2048, d_out, 2048, 2048);
  }
}